// Round 2
// baseline (4527.702 us; speedup 1.0000x reference)
//
#include <hip/hip_runtime.h>

#define INV_SQRT2f 0.70710678118654752440f
#define INV_SQRT3f 0.57735026918962576451f

typedef __bf16 bf16x8 __attribute__((ext_vector_type(8)));
typedef float f32x4 __attribute__((ext_vector_type(4)));

__device__ __forceinline__ float silu_f(float x) { return x / (1.0f + __expf(-x)); }

enum { EPI_SILU = 0, EPI_SILU_MUL = 1, EPI_ACC = 2, EPI_RES = 3, EPI_RES2 = 4 };

// ---------------------------------------------------------------------------
// Tiled bf16-MFMA GEMM: C[M,N] = epilogue(A[M,K] @ W[K,N])
// 128x128 tile, BK=32, 4 waves each computing 64x64 via 4x4 mfma_f32_16x16x32_bf16.
// A,W are f32 in global; converted to bf16 during LDS staging (fp32 accum).
// Fragment layouts (HW-verified on gfx950):
//   A: m=lane&15, k=(lane>>4)*8+j  (8 contiguous bf16 -> ds_read_b128)
//   B: n=lane&15, k=(lane>>4)*8+j  (staged transposed: Bs[n][k])
//   C/D: col=lane&15, row=(lane>>4)*4+reg
// EPI_RES/EPI_RES2 may have C == res0/res1 (in-place): each element is read
// and written by exactly one thread, and res* are never the A operand.
template <int EPI, bool CONCAT>
__global__ __launch_bounds__(256) void gemm_k(
    const float* A, const float* W, float* C, int M, int N, int K,
    const float* mul, const int* perm, const float* res0, const float* res1,
    float scale, const float* h_src, const int* gidx_s, const int* gidx_t,
    const float* m_src)
{
  constexpr int LSTR = 40;            // 32 + 8 pad; 80B rows: 16B-aligned, low-conflict
  __shared__ __bf16 As[128 * LSTR];
  __shared__ __bf16 Bs[128 * LSTR];
  const int tid  = threadIdx.x;
  const int lane = tid & 63;
  const int wave = tid >> 6;
  const int bm = blockIdx.x << 7;
  const int bn = blockIdx.y << 7;
  const int wm = (wave & 1) << 6;
  const int wn = (wave >> 1) << 6;
  const int fm = lane & 15;
  const int qk = (lane >> 4) << 3;

  f32x4 acc[4][4] = {};

  const int nkt = K >> 5;
  for (int kt = 0; kt < nkt; ++kt) {
    const int k0 = kt << 5;
    // ---- stage A tile (128x32 f32 -> bf16), 4 float4 per thread ----
#pragma unroll
    for (int i = 0; i < 4; ++i) {
      const int f   = tid + (i << 8);
      const int row = f >> 3;
      const int c4  = (f & 7) << 2;
      int gm = bm + row;
      if (gm >= M) gm = M - 1;              // clamp; stores are guarded
      const int gk = k0 + c4;
      float4 v;
      if (CONCAT) {
        // A row = [ h[idx_s[e]] (128) | h[idx_t[e]] (128) | m_after[e] (512) ]
        const float* src;
        if (gk < 128)      src = h_src + ((size_t)gidx_s[gm] << 7) + gk;
        else if (gk < 256) src = h_src + ((size_t)gidx_t[gm] << 7) + (gk - 128);
        else               src = m_src + ((size_t)gm << 9) + (gk - 256);
        v = *(const float4*)src;
      } else {
        v = *(const float4*)(A + (size_t)gm * K + gk);
      }
      __bf16* dst = &As[row * LSTR + c4];
      dst[0] = (__bf16)v.x; dst[1] = (__bf16)v.y;
      dst[2] = (__bf16)v.z; dst[3] = (__bf16)v.w;
    }
    // ---- stage B tile (32x128 f32 -> bf16, transposed into Bs[n][k]) ----
#pragma unroll
    for (int i = 0; i < 4; ++i) {
      const int f  = tid + (i << 8);
      const int kk = f >> 5;
      const int n4 = (f & 31) << 2;
      int gn = bn + n4;
      if (gn > N - 4) gn = N - 4;           // clamp (N multiple of 4); stores guarded
      const float4 v = *(const float4*)(W + (size_t)(k0 + kk) * N + gn);
      Bs[(n4 + 0) * LSTR + kk] = (__bf16)v.x;
      Bs[(n4 + 1) * LSTR + kk] = (__bf16)v.y;
      Bs[(n4 + 2) * LSTR + kk] = (__bf16)v.z;
      Bs[(n4 + 3) * LSTR + kk] = (__bf16)v.w;
    }
    __syncthreads();
    bf16x8 af[4], bfv[4];
#pragma unroll
    for (int mt = 0; mt < 4; ++mt)
      af[mt] = *(const bf16x8*)&As[(wm + mt * 16 + fm) * LSTR + qk];
#pragma unroll
    for (int nt = 0; nt < 4; ++nt)
      bfv[nt] = *(const bf16x8*)&Bs[(wn + nt * 16 + fm) * LSTR + qk];
#pragma unroll
    for (int mt = 0; mt < 4; ++mt)
#pragma unroll
      for (int nt = 0; nt < 4; ++nt)
        acc[mt][nt] = __builtin_amdgcn_mfma_f32_16x16x32_bf16(af[mt], bfv[nt], acc[mt][nt], 0, 0, 0);
    __syncthreads();
  }

  // ---- epilogue ----
#pragma unroll
  for (int mt = 0; mt < 4; ++mt) {
#pragma unroll
    for (int nt = 0; nt < 4; ++nt) {
#pragma unroll
      for (int r = 0; r < 4; ++r) {
        const int row = bm + wm + mt * 16 + ((lane >> 4) << 2) + r;
        const int col = bn + wn + nt * 16 + fm;
        if (row < M && col < N) {
          const float s = acc[mt][nt][r];
          const size_t o = (size_t)row * N + col;
          if constexpr (EPI == EPI_SILU) {
            C[o] = silu_f(s) * scale;
          } else if constexpr (EPI == EPI_SILU_MUL) {
            C[o] = silu_f(s) * mul[o];
          } else if constexpr (EPI == EPI_ACC) {
            const int rr = perm ? perm[row] : row;   // inverse-permutation scatter for [id_swap]
            C[(size_t)rr * N + col] += silu_f(s) * scale;
          } else if constexpr (EPI == EPI_RES) {
            C[o] = (res0[o] + silu_f(s)) * scale;
          } else { // EPI_RES2: (res0 + (res1 + silu(S))/sqrt2)/sqrt2
            C[o] = (res0[o] + (res1[o] + silu_f(s)) * INV_SQRT2f) * INV_SQRT2f;
          }
        }
      }
    }
  }
}

// ---------------------------------------------------------------------------
// C[M,512] = rbf[M,16] @ W[16,512]   (memory-bound K=16 projection)
__global__ __launch_bounds__(256) void rbf_proj_k(
    const float* __restrict__ rbf, const float* __restrict__ W,
    float* __restrict__ out, int M)
{
  const int g = blockIdx.x * 256 + threadIdx.x;
  const int e = g >> 9, c = g & 511;
  if (e >= M) return;
  const float* r = rbf + (size_t)e * 16;
  float s = 0.0f;
#pragma unroll
  for (int j = 0; j < 16; ++j) s += r[j] * W[(j << 9) + c];
  out[g] = s;
}

// ---------------------------------------------------------------------------
// BI[i, 0:64] = XQE[id4_expand_intm_db[i]] * (cbf4[i] @ Wq_cbf)   (400000 rows)
__global__ __launch_bounds__(256) void quad_interm_k(
    const float* __restrict__ xqe, const float* __restrict__ cbf,
    const float* __restrict__ Wcbf, const int* __restrict__ idb,
    float* __restrict__ out)
{
  __shared__ float Ws[1024];   // 16x64
  const int t = threadIdx.x;
  for (int i = t; i < 1024; i += 256) Ws[i] = Wcbf[i];
  __syncthreads();
  const int i = blockIdx.x * 4 + (t >> 6);
  const int c = t & 63;
  const float* cb = cbf + (size_t)i * 16;
  float s = 0.0f;
#pragma unroll
  for (int j = 0; j < 16; ++j) s += cb[j] * Ws[j * 64 + c];
  out[(size_t)i * 64 + c] = xqe[(size_t)idb[i] * 64 + c] * s;
}

// ---------------------------------------------------------------------------
// Quad bilinear, 8 edges/block.
// per edge: val[k=16][h=64] = BI[abd[e*16+k]];  sumk[n=16][h]=sph^T val;
// r[i=32][h]=rbfW sumk;  out[u=32] = sum_{i,h} r[i][h]*Wbil[h][i][u]
__global__ __launch_bounds__(256) void quad_bil_k(
    const float* __restrict__ BI, const float* __restrict__ sph,
    const float* __restrict__ rbfW, const float* __restrict__ Wbil,
    const int* __restrict__ abd, float* __restrict__ out)
{
  __shared__ float val[16][64];
  __shared__ float sumk[16][64];
  __shared__ __bf16 r8[8][2048];   // [ee][i*64+h]
  __shared__ float sp[16][16];
  __shared__ float rw[32][16];
  const int t = threadIdx.x;
  const int e0 = blockIdx.x * 8;
  for (int ee = 0; ee < 8; ++ee) {
    const int e = e0 + ee;
    {
      const int k = t >> 4, c4 = (t & 15) << 2;
      const int src = abd[e * 16 + k];
      *(float4*)&val[k][c4] = *(const float4*)(BI + (size_t)src * 64 + c4);
    }
    sp[t >> 4][t & 15] = sph[(size_t)e * 256 + t];
    for (int i = t; i < 512; i += 256) rw[i >> 4][i & 15] = rbfW[(size_t)e * 512 + i];
    __syncthreads();
    {
      const int h = t & 63;
      for (int n = t >> 6; n < 16; n += 4) {
        float s = 0.0f;
#pragma unroll
        for (int k = 0; k < 16; ++k) s += sp[k][n] * val[k][h];
        sumk[n][h] = s;
      }
    }
    __syncthreads();
    {
      const int h = t & 63;
      for (int i = t >> 6; i < 32; i += 4) {
        float s = 0.0f;
#pragma unroll
        for (int n = 0; n < 16; ++n) s += rw[i][n] * sumk[n][h];
        r8[ee][i * 64 + h] = (__bf16)s;
      }
    }
    __syncthreads();
  }
  // final contraction: one streaming pass over Wbil (256KB, L2-hot) per block
  const int u = t & 31, ee = t >> 5;
  float s = 0.0f;
  for (int h = 0; h < 64; ++h) {
#pragma unroll
    for (int i = 0; i < 32; ++i)
      s += (float)r8[ee][i * 64 + h] * Wbil[((size_t)(h * 32 + i)) * 32 + u];
  }
  out[(size_t)(e0 + ee) * 32 + u] = s;
}

// ---------------------------------------------------------------------------
// Triplet bilinear, 8 edges/block. val gathered from edge-level XTE via id3_expand_ba.
__global__ __launch_bounds__(256) void trip_bil_k(
    const float* __restrict__ XTE, const float* __restrict__ sph,
    const float* __restrict__ rbfW, const float* __restrict__ Wbil,
    const int* __restrict__ ba, float* __restrict__ out)
{
  __shared__ float val[16][64];
  __shared__ float sumk[7][64];
  __shared__ __bf16 r8[8][1024];   // [ee][i*64+h], i<16
  __shared__ float sp[16][7];
  __shared__ float rw[16][7];
  const int t = threadIdx.x;
  const int e0 = blockIdx.x * 8;
  for (int ee = 0; ee < 8; ++ee) {
    const int e = e0 + ee;
    {
      const int k = t >> 4, c4 = (t & 15) << 2;
      const int src = ba[e * 16 + k];
      *(float4*)&val[k][c4] = *(const float4*)(XTE + (size_t)src * 64 + c4);
    }
    if (t < 112) sp[t / 7][t % 7] = sph[(size_t)e * 112 + t];
    if (t >= 128 && t < 240) { const int q = t - 128; rw[q / 7][q % 7] = rbfW[(size_t)e * 112 + q]; }
    __syncthreads();
    {
      const int h = t & 63;
      for (int n = t >> 6; n < 7; n += 4) {
        float s = 0.0f;
#pragma unroll
        for (int k = 0; k < 16; ++k) s += sp[k][n] * val[k][h];
        sumk[n][h] = s;
      }
    }
    __syncthreads();
    {
      const int h = t & 63;
      for (int i = t >> 6; i < 16; i += 4) {
        float s = 0.0f;
#pragma unroll
        for (int n = 0; n < 7; ++n) s += rw[i][n] * sumk[n][h];
        r8[ee][i * 64 + h] = (__bf16)s;
      }
    }
    __syncthreads();
  }
  // final: each thread handles ee and ee+4 in one Wbil sweep
  const int u = t & 63, eb = t >> 6;
  float s0 = 0.0f, s1 = 0.0f;
  for (int h = 0; h < 64; ++h) {
#pragma unroll
    for (int i = 0; i < 16; ++i) {
      const float w = Wbil[((size_t)(h * 16 + i)) * 64 + u];
      s0 += (float)r8[eb][i * 64 + h] * w;
      s1 += (float)r8[eb + 4][i * 64 + h] * w;
    }
  }
  out[(size_t)(e0 + eb) * 64 + u] = s0;
  out[(size_t)(e0 + eb + 4) * 64 + u] = s1;
}

// ---------------------------------------------------------------------------
__global__ __launch_bounds__(256) void inv_perm_k(const int* __restrict__ p,
                                                  int* __restrict__ inv, int n)
{
  const int i = blockIdx.x * 256 + threadIdx.x;
  if (i < n) inv[p[i]] = i;
}

__global__ __launch_bounds__(256) void zero_k(float* __restrict__ p, int n)
{
  const int i = blockIdx.x * 256 + threadIdx.x;
  if (i < n) p[i] = 0.0f;
}

// segment-sum scatter: A0[idx_t[e], c] += m_after[e,c] * rh[e,c]
__global__ __launch_bounds__(256) void atom_scatter_k(
    const float* __restrict__ mafter, const float* __restrict__ rh,
    const int* __restrict__ idxt, float* __restrict__ A0, int nE)
{
  const int g = blockIdx.x * 256 + threadIdx.x;
  const int e = g >> 9, c = g & 511;
  if (e >= nE) return;
  const size_t o = (size_t)e * 512 + c;
  atomicAdd(&A0[(size_t)idxt[e] * 512 + c], mafter[o] * rh[o]);
}

__global__ __launch_bounds__(256) void hout_k(const float* __restrict__ h,
                                              const float* __restrict__ xa,
                                              float* __restrict__ out, int n)
{
  const int i = blockIdx.x * 256 + threadIdx.x;
  if (i < n) out[i] = (h[i] + xa[i]) * INV_SQRT2f;
}

// ---------------------------------------------------------------------------
extern "C" void kernel_launch(void* const* d_in, const int* in_sizes, int n_in,
                              void* d_out, int out_size, void* d_ws, size_t ws_size,
                              hipStream_t stream) {
  (void)in_sizes; (void)n_in; (void)out_size; (void)ws_size;
  const float* h        = (const float*)d_in[0];
  const float* m        = (const float*)d_in[1];
  const float* rbf4     = (const float*)d_in[2];
  const float* cbf4     = (const float*)d_in[3];
  const float* rbfW4    = (const float*)d_in[4];
  const float* sph4     = (const float*)d_in[5];
  const float* rbf3     = (const float*)d_in[6];
  const float* rbfW3    = (const float*)d_in[7];
  const float* sph3     = (const float*)d_in[8];
  const float* rbf_h    = (const float*)d_in[9];
  const float* W_dense  = (const float*)d_in[10];
  const float* Wq_db    = (const float*)d_in[11];
  const float* Wq_rbf   = (const float*)d_in[12];
  const float* Wq_cbf   = (const float*)d_in[13];
  const float* Wq_bil   = (const float*)d_in[14];
  const float* Wq_down  = (const float*)d_in[15];
  const float* Wq_up_ca = (const float*)d_in[16];
  const float* Wq_up_ac = (const float*)d_in[17];
  const float* Wt_ba    = (const float*)d_in[18];
  const float* Wt_rbf   = (const float*)d_in[19];
  const float* Wt_bil   = (const float*)d_in[20];
  const float* Wt_down  = (const float*)d_in[21];
  const float* Wt_up_ca = (const float*)d_in[22];
  const float* Wt_up_ac = (const float*)d_in[23];
  const float* W_before = (const float*)d_in[24];
  const float* W_after  = (const float*)d_in[25];
  const float* W_au_rbf = (const float*)d_in[26];
  const float* W_au_dns = (const float*)d_in[27];
  const float* W_au_res = (const float*)d_in[28];
  const float* W_concat = (const float*)d_in[29];
  const float* W_resm   = (const float*)d_in[30];
  const int* id_swap    = (const int*)d_in[32];
  const int* id4_db     = (const int*)d_in[34];
  const int* id4_abd    = (const int*)d_in[35];
  const int* id3_ba     = (const int*)d_in[37];
  const int* idx_s      = (const int*)d_in[39];
  const int* idx_t      = (const int*)d_in[40];

  // ---- workspace layout (floats), liveness-overlapped; total ~224 MiB ----
  // B0, B1: 50000x512 ping-pong.  XQE/XTE alias B1's later life.
  // R region: XQB/XTB early, A0/A1/A2 (atom phase) later.
  // BI (400000x64) and the m_after "X" buffer live in d_out's m region.
  float* w = (float*)d_ws;
  const size_t S = 25600000;                 // 50000*512
  float* B0  = w;
  float* B1  = w + S;
  float* XQE = B1;                           // 50000*64, alias (B1 free at that point)
  float* XTE = B1;                           // 50000*64, alias
  float* R   = w + 2 * S;                    // 4.8M floats
  float* XQB = R;                            // 50000*32 = 1.6M
  float* XTB = R + 1600000;                  // 50000*64 = 3.2M
  float* A0  = R;                            // 5000*512 = 2.56M (after XQB/XTB dead)
  float* A1  = R + 2560000;                  // 5000*128
  float* A2  = R + 3200000;                  // 5000*128
  int*   INV = (int*)(R + 4800000);          // 50000 ints

  float* out_h = (float*)d_out;              // 5000*128
  float* out_m = out_h + 640000;             // 50000*512 — doubles as BI, then X (m_after)
  float* BI    = out_m;                      // 400000*64 = 25.6M exactly

  const float s23 = INV_SQRT2f * INV_SQRT3f;
  const dim3 blk(256);
  const dim3 gFull(391, 4), gN64(391, 1), gAtom(40, 1);
#define NUL9 nullptr, nullptr, nullptr, nullptr
#define TAIL4 nullptr, nullptr, nullptr, nullptr

  inv_perm_k<<<196, blk, 0, stream>>>(id_swap, INV, 50000);

  // ---- quadruplet branch ----
  rbf_proj_k<<<100000, blk, 0, stream>>>(rbf4, Wq_rbf, B1, 50000);
  gemm_k<EPI_SILU_MUL, false><<<gFull, blk, 0, stream>>>(m, Wq_db, B0, 50000, 512, 512,
      B1, nullptr, nullptr, nullptr, 1.0f, TAIL4);
  gemm_k<EPI_SILU, false><<<gN64, blk, 0, stream>>>(B0, Wq_down, XQE, 50000, 64, 512,
      NUL9, 1.0f, TAIL4);
  quad_interm_k<<<100000, blk, 0, stream>>>(XQE, cbf4, Wq_cbf, id4_db, BI);
  quad_bil_k<<<6250, blk, 0, stream>>>(BI, sph4, rbfW4, Wq_bil, id4_abd, XQB);

  // ---- triplet branch ----
  rbf_proj_k<<<100000, blk, 0, stream>>>(rbf3, Wt_rbf, B1, 50000);
  gemm_k<EPI_SILU_MUL, false><<<gFull, blk, 0, stream>>>(m, Wt_ba, B0, 50000, 512, 512,
      B1, nullptr, nullptr, nullptr, 1.0f, TAIL4);
  gemm_k<EPI_SILU, false><<<gN64, blk, 0, stream>>>(B0, Wt_down, XTE, 50000, 64, 512,
      NUL9, 1.0f, TAIL4);
  trip_bil_k<<<6250, blk, 0, stream>>>(XTE, sph3, rbfW3, Wt_bil, id3_ba, XTB);

  // ---- merge: x = (x_ca + x4 + x3)/sqrt3, up-projections accumulate in epilogue ----
  gemm_k<EPI_SILU, false><<<gFull, blk, 0, stream>>>(m, W_dense, B0, 50000, 512, 512,
      NUL9, INV_SQRT3f, TAIL4);
  gemm_k<EPI_ACC, false><<<gFull, blk, 0, stream>>>(XQB, Wq_up_ca, B0, 50000, 512, 32,
      nullptr, nullptr, nullptr, nullptr, s23, TAIL4);
  gemm_k<EPI_ACC, false><<<gFull, blk, 0, stream>>>(XQB, Wq_up_ac, B0, 50000, 512, 32,
      nullptr, INV, nullptr, nullptr, s23, TAIL4);
  gemm_k<EPI_ACC, false><<<gFull, blk, 0, stream>>>(XTB, Wt_up_ca, B0, 50000, 512, 64,
      nullptr, nullptr, nullptr, nullptr, s23, TAIL4);
  gemm_k<EPI_ACC, false><<<gFull, blk, 0, stream>>>(XTB, Wt_up_ac, B0, 50000, 512, 64,
      nullptr, INV, nullptr, nullptr, s23, TAIL4);

  // ---- W_before (1 layer) + m add -> X := out_m; then W_after (2 layers, in place) ----
  gemm_k<EPI_SILU, false><<<gFull, blk, 0, stream>>>(B0, W_before, B1, 50000, 512, 512,
      NUL9, 1.0f, TAIL4);
  gemm_k<EPI_RES2, false><<<gFull, blk, 0, stream>>>(B1, W_before + 262144, out_m, 50000, 512, 512,
      nullptr, nullptr, m, B0, 1.0f, TAIL4);
  gemm_k<EPI_SILU, false><<<gFull, blk, 0, stream>>>(out_m, W_after, B1, 50000, 512, 512,
      NUL9, 1.0f, TAIL4);
  gemm_k<EPI_RES, false><<<gFull, blk, 0, stream>>>(B1, W_after + 262144, out_m, 50000, 512, 512,
      nullptr, nullptr, out_m, nullptr, INV_SQRT2f, TAIL4);
  gemm_k<EPI_SILU, false><<<gFull, blk, 0, stream>>>(out_m, W_after + 524288, B1, 50000, 512, 512,
      NUL9, 1.0f, TAIL4);
  gemm_k<EPI_RES, false><<<gFull, blk, 0, stream>>>(B1, W_after + 786432, out_m, 50000, 512, 512,
      nullptr, nullptr, out_m, nullptr, INV_SQRT2f, TAIL4);
  // out_m = m_after

  // ---- atom update ----
  rbf_proj_k<<<100000, blk, 0, stream>>>(rbf_h, W_au_rbf, B1, 50000);
  zero_k<<<10000, blk, 0, stream>>>(A0, 2560000);
  atom_scatter_k<<<100000, blk, 0, stream>>>(out_m, B1, idx_t, A0, 50000);
  gemm_k<EPI_SILU, false><<<gAtom, blk, 0, stream>>>(A0, W_au_dns, A1, 5000, 128, 512,
      NUL9, 1.0f, TAIL4);
  for (int l = 0; l < 3; ++l) {
    gemm_k<EPI_SILU, false><<<gAtom, blk, 0, stream>>>(A1, W_au_res + (size_t)(2 * l) * 16384,
        A2, 5000, 128, 128, NUL9, 1.0f, TAIL4);
    gemm_k<EPI_RES, false><<<gAtom, blk, 0, stream>>>(A2, W_au_res + (size_t)(2 * l + 1) * 16384,
        A1, 5000, 128, 128, nullptr, nullptr, A1, nullptr, INV_SQRT2f, TAIL4);
  }
  hout_k<<<2500, blk, 0, stream>>>(h, A1, out_h, 640000);

  // ---- concat re-embedding + W_resm, final m write (in place on out_m) ----
  gemm_k<EPI_SILU, true><<<gFull, blk, 0, stream>>>(nullptr, W_concat, B0, 50000, 512, 768,
      nullptr, nullptr, nullptr, nullptr, 1.0f, out_h, idx_s, idx_t, out_m);
  gemm_k<EPI_SILU, false><<<gFull, blk, 0, stream>>>(B0, W_resm, B1, 50000, 512, 512,
      NUL9, 1.0f, TAIL4);
  gemm_k<EPI_RES2, false><<<gFull, blk, 0, stream>>>(B1, W_resm + 262144, out_m, 50000, 512, 512,
      nullptr, nullptr, out_m, B0, 1.0f, TAIL4);
#undef NUL9
#undef TAIL4
}